// Round 8
// baseline (765.216 us; speedup 1.0000x reference)
//
#include <hip/hip_runtime.h>
#include <hip/hip_bf16.h>

#define HID 16
#define NFEAT 512
#define BW 64           // nodes per bucket (dst >> 6)
#define CH 16384        // edges per histogram/scatter block
#define MAXB 2048       // max buckets supported by bucket path

typedef __attribute__((ext_vector_type(8))) short bf16x8;
typedef __attribute__((ext_vector_type(4))) float f32x4;

__device__ __forceinline__ unsigned short f2b_hw(float f) {
    __hip_bfloat16 h = __float2bfloat16(f);
    return *reinterpret_cast<unsigned short*>(&h);
}
__device__ __forceinline__ float b2f(unsigned short b) {
    return __uint_as_float(((unsigned)b) << 16);
}

// ================= bucket build =================
__global__ __launch_bounds__(1024) void khist(const int* __restrict__ dst,
                                              int* __restrict__ gcount, int e, int nbkt) {
    __shared__ int hist[MAXB];
    for (int t = threadIdx.x; t < nbkt; t += 1024) hist[t] = 0;
    __syncthreads();
    int base = blockIdx.x * CH;
#pragma unroll
    for (int k = 0; k < CH / 1024; ++k) {
        int i = base + k * 1024 + threadIdx.x;
        if (i < e) atomicAdd(&hist[dst[i] >> 6], 1);
    }
    __syncthreads();
    for (int t = threadIdx.x; t < nbkt; t += 1024)
        if (hist[t]) atomicAdd(&gcount[t], hist[t]);
}

// single-block exclusive scan of gcount[0..nbkt) -> goff, gcursor; goff[nbkt]=e
__global__ __launch_bounds__(1024) void kscan(const int* __restrict__ gcount,
                                              int* __restrict__ goff,
                                              int* __restrict__ gcursor, int nbkt) {
    __shared__ int buf0[MAXB], buf1[MAXB];
    for (int t = threadIdx.x; t < MAXB; t += 1024) buf0[t] = (t < nbkt) ? gcount[t] : 0;
    __syncthreads();
    int* in = buf0; int* out = buf1;
    for (int d = 1; d < MAXB; d <<= 1) {
        for (int t = threadIdx.x; t < MAXB; t += 1024)
            out[t] = in[t] + (t >= d ? in[t - d] : 0);
        __syncthreads();
        int* tmp = in; in = out; out = tmp;
    }
    for (int t = threadIdx.x; t < nbkt; t += 1024) {
        int excl = in[t] - gcount[t];
        goff[t] = excl;
        gcursor[t] = excl;
    }
    if (threadIdx.x == 0) goff[nbkt] = in[nbkt - 1];
}

// LDS-presorted scatter: per-block bucket counts -> one reservation atomic per
// (block,bucket) (~300k transactions vs 3.2M), then contiguous slot writes.
__global__ __launch_bounds__(1024) void kscatter(const int* __restrict__ src,
                                                 const int* __restrict__ dst,
                                                 int* __restrict__ gcursor,
                                                 int2* __restrict__ pairs, int e, int nbkt) {
    __shared__ int hist[MAXB];
    __shared__ int base[MAXB];
    for (int t = threadIdx.x; t < nbkt; t += 1024) hist[t] = 0;
    __syncthreads();
    int b0 = blockIdx.x * CH;
#pragma unroll
    for (int k = 0; k < CH / 1024; ++k) {
        int i = b0 + k * 1024 + threadIdx.x;
        if (i < e) atomicAdd(&hist[dst[i] >> 6], 1);
    }
    __syncthreads();
    for (int t = threadIdx.x; t < nbkt; t += 1024)
        base[t] = hist[t] ? atomicAdd(&gcursor[t], hist[t]) : 0;
    __syncthreads();
#pragma unroll
    for (int k = 0; k < CH / 1024; ++k) {
        int i = b0 + k * 1024 + threadIdx.x;
        if (i < e) {
            int d = dst[i];
            int pos = atomicAdd(&base[d >> 6], 1);   // LDS bump
            pairs[pos] = make_int2(src[i], d);
        }
    }
}

// ================= per-bucket degree (no global atomics) =================
__global__ __launch_bounds__(256) void kdeg(const int2* __restrict__ pairs,
                                            const int* __restrict__ goff,
                                            float* __restrict__ dis, int n) {
    __shared__ int cnt[BW];
    int b = blockIdx.x;
    if (threadIdx.x < BW) cnt[threadIdx.x] = 0;
    __syncthreads();
    int s0 = goff[b], s1 = goff[b + 1];
    for (int i = s0 + threadIdx.x; i < s1; i += 256)
        atomicAdd(&cnt[pairs[i].y & (BW - 1)], 1);
    __syncthreads();
    if (threadIdx.x < BW) {
        int node = b * BW + threadIdx.x;
        if (node < n) dis[node] = rsqrtf(1.0f + (float)cnt[threadIdx.x]);
    }
}

// ================= W1 -> Wt (bf16 transposed) =================
__global__ __launch_bounds__(256) void prep_wt(const float* __restrict__ W1,
                                               unsigned short* __restrict__ Wt) {
    int i = blockIdx.x * 256 + threadIdx.x;   // 8192 = 16*512
    int j = i >> 9, k = i & 511;
    Wt[i] = f2b_hw(W1[k * HID + j]);
}

// ================= h1 = x @ W1 via MFMA (proven round 7) =================
__global__ __launch_bounds__(256) void mm1_mfma(const float* __restrict__ x,
                                                const unsigned short* __restrict__ Wt,
                                                const float* __restrict__ dis,
                                                float* __restrict__ h1,
                                                unsigned short* __restrict__ hsb, int n) {
    int wid  = threadIdx.x >> 6;
    int lane = threadIdx.x & 63;
    int base = (blockIdx.x * 4 + wid) * 16;
    if (base >= n) return;
    int lrow = lane & 15;
    int kg   = lane >> 4;

    bf16x8 bfr[16];
#pragma unroll
    for (int t = 0; t < 16; ++t)
        bfr[t] = *(const bf16x8*)(Wt + lrow * NFEAT + t * 32 + kg * 8);

    int row = base + lrow;
    bool ok = (row < n);
    const float* xr = x + (size_t)(ok ? row : 0) * NFEAT;

    f32x4 acc = {0.f, 0.f, 0.f, 0.f};
#pragma unroll
    for (int t = 0; t < 16; ++t) {
        float4 u0 = *(const float4*)(xr + t * 32 + kg * 8);
        float4 u1 = *(const float4*)(xr + t * 32 + kg * 8 + 4);
        if (!ok) { u0 = make_float4(0,0,0,0); u1 = make_float4(0,0,0,0); }
        union { bf16x8 v; unsigned short u[8]; } A;
        A.u[0] = f2b_hw(u0.x); A.u[1] = f2b_hw(u0.y);
        A.u[2] = f2b_hw(u0.z); A.u[3] = f2b_hw(u0.w);
        A.u[4] = f2b_hw(u1.x); A.u[5] = f2b_hw(u1.y);
        A.u[6] = f2b_hw(u1.z); A.u[7] = f2b_hw(u1.w);
        acc = __builtin_amdgcn_mfma_f32_16x16x32_bf16(A.v, bfr[t], acc, 0, 0, 0);
    }

#pragma unroll
    for (int q = 0; q < 4; ++q) {
        int orow = base + kg * 4 + q;
        if (orow < n) {
            float v = acc[q];
            h1[(size_t)orow * HID + lrow] = v;
            hsb[(size_t)orow * HID + lrow] = f2b_hw(v * dis[orow]);
        }
    }
}

// ================= per-bucket aggregation (no global atomics) =================
// out[v][j] = sum_{(s,v) in bucket} hs[s][j]   (raw; dis[v] applied in mid/finalk)
__global__ __launch_bounds__(256) void kagg(const int2* __restrict__ pairs,
                                            const int* __restrict__ goff,
                                            const unsigned short* __restrict__ hsb,
                                            float* __restrict__ out, int n) {
    __shared__ float acc[BW * 17];
    int b = blockIdx.x;
    for (int t = threadIdx.x; t < BW * 17; t += 256) acc[t] = 0.f;
    __syncthreads();
    int s0 = goff[b], s1 = goff[b + 1];
    int j = threadIdx.x & 15;
    for (int i = s0 + (threadIdx.x >> 4); i < s1; i += 16) {
        int2 p = pairs[i];                       // 16 lanes share one 8B load
        float v = b2f(hsb[(size_t)p.x * HID + j]);
        atomicAdd(&acc[(p.y & (BW - 1)) * 17 + j], v);   // LDS, ~2-way conflicts
    }
    __syncthreads();
#pragma unroll
    for (int r0 = 0; r0 < BW; r0 += 16) {
        int r = r0 + (threadIdx.x >> 4);
        int node = b * BW + r;
        if (node < n) out[(size_t)node * HID + j] = acc[r * 17 + j];
    }
}

// ================= fused middle / final (proven) =================
__global__ __launch_bounds__(256) void mid(const float* __restrict__ agg1,
                                           float* __restrict__ h1,
                                           unsigned short* __restrict__ hsb,
                                           const float* __restrict__ dis,
                                           const float* __restrict__ b1,
                                           const float* __restrict__ W2, int n) {
    __shared__ float W2s[HID * HID];
    W2s[threadIdx.x] = W2[threadIdx.x];
    __syncthreads();
    int idx = blockIdx.x * 256 + threadIdx.x;
    int v = idx >> 4, j = idx & 15;
    if (v >= n) return;
    float dn = dis[v];
    float a = dn * agg1[idx] + dn * dn * h1[idx] + b1[j];
    float hv = fmaxf(a, 0.f);
    float h2 = 0.f;
#pragma unroll
    for (int k = 0; k < HID; ++k)
        h2 += __shfl(hv, k, HID) * W2s[k * HID + j];
    h1[idx] = h2;
    hsb[idx] = f2b_hw(h2 * dn);
}

__global__ __launch_bounds__(256) void finalk(float* __restrict__ out,
                                              const float* __restrict__ h2,
                                              const float* __restrict__ dis,
                                              const float* __restrict__ b2,
                                              const float* __restrict__ eps, int n) {
    int idx = blockIdx.x * 256 + threadIdx.x;
    int v = idx >> 4, j = idx & 15;
    if (v >= n) return;
    float dn = dis[v];
    float z = dn * out[idx] + dn * dn * h2[idx] + b2[j];
    out[idx] = z + eps[idx] * expf(0.5f * z);
}

// ================= fallback (round-7 atomic path) =================
__global__ __launch_bounds__(256) void deg_count_int(const int* __restrict__ dst,
                                                     int* __restrict__ ideg, int e) {
    int i = blockIdx.x * 256 + threadIdx.x;
    if (i < e) atomicAdd(&ideg[dst[i]], 1);
}
__global__ __launch_bounds__(256) void make_dis(const int* __restrict__ ideg,
                                                float* __restrict__ dis, int n) {
    int i = blockIdx.x * 256 + threadIdx.x;
    if (i < n) dis[i] = rsqrtf(1.0f + (float)ideg[i]);
}
__global__ __launch_bounds__(256) void prop(const int* __restrict__ src,
                                            const int* __restrict__ dst,
                                            const unsigned short* __restrict__ hsb,
                                            float* __restrict__ agg, int e) {
    int idx = blockIdx.x * 256 + threadIdx.x;
    int ed = idx >> 4, j = idx & 15;
    if (ed >= e) return;
    int s = src[ed], d = dst[ed];
    atomicAdd(&agg[(size_t)d * HID + j], b2f(hsb[(size_t)s * HID + j]));
}

extern "C" void kernel_launch(void* const* d_in, const int* in_sizes, int n_in,
                              void* d_out, int out_size, void* d_ws, size_t ws_size,
                              hipStream_t stream) {
    const float* x   = (const float*)d_in[0];
    const float* W1  = (const float*)d_in[1];
    const float* b1  = (const float*)d_in[2];
    const float* W2  = (const float*)d_in[3];
    const float* b2  = (const float*)d_in[4];
    const float* eps = (const float*)d_in[5];
    const int*   ei  = (const int*)d_in[6];

    int n = in_sizes[5] / HID;   // 100000
    int e = in_sizes[6] / 2;     // 3200000
    const int* srcs = ei;
    const int* dsts = ei + e;
    float* outf = (float*)d_out;

    int nbkt = (n + BW - 1) / BW;            // 1563
    int nBlk    = (n + 255) / 256;
    int eBlk    = (e + 255) / 256;
    int mmBlk   = (n + 63) / 64;
    int featBlk = (n * 16 + 255) / 256;
    int chBlk   = (e + CH - 1) / CH;         // 196

    // bucket-path ws: [pairs 8e][gcount][goff][gcursor][dis 4n][h1 64n][agg1 64n][hsb 32n][Wt 16K]
    size_t needBucket = (size_t)e * 8 + 3 * (size_t)(MAXB + 2) * 4
                      + (size_t)n * 4 + (size_t)n * 64 * 2 + (size_t)n * 32 + 16384;
    bool bucketPath = (nbkt <= MAXB) && (ws_size >= needBucket);

    if (bucketPath) {
        int2*           pairs   = (int2*)d_ws;
        int*            gcount  = (int*)(pairs + e);
        int*            goff    = gcount + (MAXB + 2);
        int*            gcursor = goff + (MAXB + 2);
        float*          dis     = (float*)(gcursor + (MAXB + 2));
        float*          h1      = dis + n;
        float*          agg1    = h1 + (size_t)n * HID;
        unsigned short* hsb     = (unsigned short*)(agg1 + (size_t)n * HID);
        unsigned short* Wt      = hsb + (size_t)n * HID;

        hipMemsetAsync(gcount, 0, (size_t)(MAXB + 2) * 4, stream);
        khist<<<chBlk, 1024, 0, stream>>>(dsts, gcount, e, nbkt);
        kscan<<<1, 1024, 0, stream>>>(gcount, goff, gcursor, nbkt);
        kscatter<<<chBlk, 1024, 0, stream>>>(srcs, dsts, gcursor, pairs, e, nbkt);
        kdeg<<<nbkt, 256, 0, stream>>>(pairs, goff, dis, n);

        prep_wt<<<32, 256, 0, stream>>>(W1, Wt);
        mm1_mfma<<<mmBlk, 256, 0, stream>>>(x, Wt, dis, h1, hsb, n);

        kagg<<<nbkt, 256, 0, stream>>>(pairs, goff, hsb, agg1, n);
        mid<<<featBlk, 256, 0, stream>>>(agg1, h1, hsb, dis, b1, W2, n);
        kagg<<<nbkt, 256, 0, stream>>>(pairs, goff, hsb, outf, n);
        finalk<<<featBlk, 256, 0, stream>>>(outf, h1, dis, b2, eps, n);
    } else {
        // round-7 path
        int*            ideg = (int*)d_ws;
        float*          dis  = (float*)(ideg + n);
        float*          h1   = dis + n;
        float*          agg1 = h1 + (size_t)n * HID;
        unsigned short* hsb  = (unsigned short*)(agg1 + (size_t)n * HID);
        unsigned short* Wt   = hsb + (size_t)n * HID;

        size_t featBytes = (size_t)n * HID * sizeof(float);
        hipMemsetAsync(ideg, 0, (size_t)n * sizeof(int), stream);
        hipMemsetAsync(agg1, 0, featBytes, stream);
        hipMemsetAsync(outf, 0, featBytes, stream);

        int propBlk = (e * 16 + 255) / 256;
        prep_wt<<<32, 256, 0, stream>>>(W1, Wt);
        deg_count_int<<<eBlk, 256, 0, stream>>>(dsts, ideg, e);
        make_dis<<<nBlk, 256, 0, stream>>>(ideg, dis, n);
        mm1_mfma<<<mmBlk, 256, 0, stream>>>(x, Wt, dis, h1, hsb, n);
        prop<<<propBlk, 256, 0, stream>>>(srcs, dsts, hsb, agg1, e);
        mid<<<featBlk, 256, 0, stream>>>(agg1, h1, hsb, dis, b1, W2, n);
        prop<<<propBlk, 256, 0, stream>>>(srcs, dsts, hsb, outf, e);
        finalk<<<featBlk, 256, 0, stream>>>(outf, h1, dis, b2, eps, n);
    }
}

// Round 9
// 757.031 us; speedup vs baseline: 1.0108x; 1.0108x over previous
//
#include <hip/hip_runtime.h>
#include <hip/hip_bf16.h>

#define HID 16
#define NFEAT 512
#define BW 64           // nodes per bucket (dst >> 6)
#define CH 16384        // edges per histogram/scatter block
#define MAXB 2048       // max buckets supported by bucket path

typedef __attribute__((ext_vector_type(8))) short bf16x8;
typedef __attribute__((ext_vector_type(4))) float f32x4;

__device__ __forceinline__ unsigned short f2b_hw(float f) {
    __hip_bfloat16 h = __float2bfloat16(f);
    return *reinterpret_cast<unsigned short*>(&h);
}
__device__ __forceinline__ float b2f(unsigned short b) {
    return __uint_as_float(((unsigned)b) << 16);
}

// ================= bucket build =================
__global__ __launch_bounds__(1024) void khist(const int* __restrict__ dst,
                                              int* __restrict__ gcount, int e, int nbkt) {
    __shared__ int hist[MAXB];
    for (int t = threadIdx.x; t < nbkt; t += 1024) hist[t] = 0;
    __syncthreads();
    int base = blockIdx.x * CH;
#pragma unroll
    for (int k = 0; k < CH / 1024; ++k) {
        int i = base + k * 1024 + threadIdx.x;
        if (i < e) atomicAdd(&hist[dst[i] >> 6], 1);
    }
    __syncthreads();
    for (int t = threadIdx.x; t < nbkt; t += 1024)
        if (hist[t]) atomicAdd(&gcount[t], hist[t]);
}

__global__ __launch_bounds__(1024) void kscan(const int* __restrict__ gcount,
                                              int* __restrict__ goff,
                                              int* __restrict__ gcursor, int nbkt) {
    __shared__ int buf0[MAXB], buf1[MAXB];
    for (int t = threadIdx.x; t < MAXB; t += 1024) buf0[t] = (t < nbkt) ? gcount[t] : 0;
    __syncthreads();
    int* in = buf0; int* out = buf1;
    for (int d = 1; d < MAXB; d <<= 1) {
        for (int t = threadIdx.x; t < MAXB; t += 1024)
            out[t] = in[t] + (t >= d ? in[t - d] : 0);
        __syncthreads();
        int* tmp = in; in = out; out = tmp;
    }
    for (int t = threadIdx.x; t < nbkt; t += 1024) {
        int excl = in[t] - gcount[t];
        goff[t] = excl;
        gcursor[t] = excl;
    }
    if (threadIdx.x == 0) goff[nbkt] = in[nbkt - 1];
}

// LDS-presorted scatter of PACKED edges: pk = (src<<6) | (dst & 63).
__global__ __launch_bounds__(1024) void kscatter(const int* __restrict__ src,
                                                 const int* __restrict__ dst,
                                                 int* __restrict__ gcursor,
                                                 unsigned* __restrict__ pk, int e, int nbkt) {
    __shared__ int hist[MAXB];
    __shared__ int base[MAXB];
    for (int t = threadIdx.x; t < nbkt; t += 1024) hist[t] = 0;
    __syncthreads();
    int b0 = blockIdx.x * CH;
#pragma unroll
    for (int k = 0; k < CH / 1024; ++k) {
        int i = b0 + k * 1024 + threadIdx.x;
        if (i < e) atomicAdd(&hist[dst[i] >> 6], 1);
    }
    __syncthreads();
    for (int t = threadIdx.x; t < nbkt; t += 1024)
        base[t] = hist[t] ? atomicAdd(&gcursor[t], hist[t]) : 0;
    __syncthreads();
#pragma unroll
    for (int k = 0; k < CH / 1024; ++k) {
        int i = b0 + k * 1024 + threadIdx.x;
        if (i < e) {
            int d = dst[i];
            int pos = atomicAdd(&base[d >> 6], 1);   // LDS bump
            pk[pos] = ((unsigned)src[i] << 6) | (unsigned)(d & 63);
        }
    }
}

// ================= per-bucket degree =================
__global__ __launch_bounds__(256) void kdeg(const unsigned* __restrict__ pk,
                                            const int* __restrict__ goff,
                                            float* __restrict__ dis, int n) {
    __shared__ int cnt[BW];
    int b = blockIdx.x;
    if (threadIdx.x < BW) cnt[threadIdx.x] = 0;
    __syncthreads();
    int s0 = goff[b], s1 = goff[b + 1];
    for (int i = s0 + threadIdx.x; i < s1; i += 256)
        atomicAdd(&cnt[pk[i] & 63], 1);
    __syncthreads();
    if (threadIdx.x < BW) {
        int node = b * BW + threadIdx.x;
        if (node < n) dis[node] = rsqrtf(1.0f + (float)cnt[threadIdx.x]);
    }
}

// ================= W1 -> Wt (bf16 transposed) =================
__global__ __launch_bounds__(256) void prep_wt(const float* __restrict__ W1,
                                               unsigned short* __restrict__ Wt) {
    int i = blockIdx.x * 256 + threadIdx.x;   // 8192 = 16*512
    int j = i >> 9, k = i & 511;
    Wt[i] = f2b_hw(W1[k * HID + j]);
}

// ================= h1 = x @ W1 via MFMA (proven) =================
__global__ __launch_bounds__(256) void mm1_mfma(const float* __restrict__ x,
                                                const unsigned short* __restrict__ Wt,
                                                const float* __restrict__ dis,
                                                float* __restrict__ h1,
                                                unsigned short* __restrict__ hsb, int n) {
    int wid  = threadIdx.x >> 6;
    int lane = threadIdx.x & 63;
    int base = (blockIdx.x * 4 + wid) * 16;
    if (base >= n) return;
    int lrow = lane & 15;
    int kg   = lane >> 4;

    bf16x8 bfr[16];
#pragma unroll
    for (int t = 0; t < 16; ++t)
        bfr[t] = *(const bf16x8*)(Wt + lrow * NFEAT + t * 32 + kg * 8);

    int row = base + lrow;
    bool ok = (row < n);
    const float* xr = x + (size_t)(ok ? row : 0) * NFEAT;

    f32x4 acc = {0.f, 0.f, 0.f, 0.f};
#pragma unroll
    for (int t = 0; t < 16; ++t) {
        float4 u0 = *(const float4*)(xr + t * 32 + kg * 8);
        float4 u1 = *(const float4*)(xr + t * 32 + kg * 8 + 4);
        if (!ok) { u0 = make_float4(0,0,0,0); u1 = make_float4(0,0,0,0); }
        union { bf16x8 v; unsigned short u[8]; } A;
        A.u[0] = f2b_hw(u0.x); A.u[1] = f2b_hw(u0.y);
        A.u[2] = f2b_hw(u0.z); A.u[3] = f2b_hw(u0.w);
        A.u[4] = f2b_hw(u1.x); A.u[5] = f2b_hw(u1.y);
        A.u[6] = f2b_hw(u1.z); A.u[7] = f2b_hw(u1.w);
        acc = __builtin_amdgcn_mfma_f32_16x16x32_bf16(A.v, bfr[t], acc, 0, 0, 0);
    }

#pragma unroll
    for (int q = 0; q < 4; ++q) {
        int orow = base + kg * 4 + q;
        if (orow < n) {
            float v = acc[q];
            h1[(size_t)orow * HID + lrow] = v;
            hsb[(size_t)orow * HID + lrow] = f2b_hw(v * dis[orow]);
        }
    }
}

// ================= per-bucket aggregation, MLP version =================
// Stage 256 packed edges in LDS (coalesced), then FULLY-UNROLLED 16-step loop:
// each 16-lane group has up to 16 independent hsb gathers in flight (round-8's
// kagg had 1 -> latency-bound at 303us). LDS accumulate, plain stores.
__global__ __launch_bounds__(256) void kagg(const unsigned* __restrict__ pk,
                                            const int* __restrict__ goff,
                                            const unsigned short* __restrict__ hsb,
                                            float* __restrict__ out, int n) {
    __shared__ float acc[BW * 17];
    __shared__ unsigned stage[256];
    int b = blockIdx.x;
    for (int t = threadIdx.x; t < BW * 17; t += 256) acc[t] = 0.f;
    int s0 = goff[b], s1 = goff[b + 1];
    int g = threadIdx.x >> 4, j = threadIdx.x & 15;
    __syncthreads();

    for (int base = s0; base < s1; base += 256) {
        int i = base + threadIdx.x;
        if (i < s1) stage[threadIdx.x] = pk[i];
        int cnt = min(256, s1 - base);
        __syncthreads();
#pragma unroll
        for (int u = 0; u < 16; ++u) {
            int r = u * 16 + g;
            if (r < cnt) {
                unsigned v = stage[r];
                float val = b2f(hsb[(size_t)(v >> 6) * HID + j]);
                atomicAdd(&acc[(v & 63u) * 17 + j], val);
            }
        }
        __syncthreads();
    }

#pragma unroll
    for (int r0 = 0; r0 < BW; r0 += 16) {
        int r = r0 + g;
        int node = b * BW + r;
        if (node < n) out[(size_t)node * HID + j] = acc[r * 17 + j];
    }
}

// ================= fused middle / final =================
__global__ __launch_bounds__(256) void mid(const float* __restrict__ agg1,
                                           float* __restrict__ h1,
                                           unsigned short* __restrict__ hsb,
                                           const float* __restrict__ dis,
                                           const float* __restrict__ b1,
                                           const float* __restrict__ W2, int n) {
    __shared__ float W2s[HID * HID];
    W2s[threadIdx.x] = W2[threadIdx.x];
    __syncthreads();
    int idx = blockIdx.x * 256 + threadIdx.x;
    int v = idx >> 4, j = idx & 15;
    if (v >= n) return;
    float dn = dis[v];
    float a = dn * agg1[idx] + dn * dn * h1[idx] + b1[j];
    float hv = fmaxf(a, 0.f);
    float h2 = 0.f;
#pragma unroll
    for (int k = 0; k < HID; ++k)
        h2 += __shfl(hv, k, HID) * W2s[k * HID + j];
    h1[idx] = h2;
    hsb[idx] = f2b_hw(h2 * dn);
}

__global__ __launch_bounds__(256) void finalk(float* __restrict__ out,
                                              const float* __restrict__ h2,
                                              const float* __restrict__ dis,
                                              const float* __restrict__ b2,
                                              const float* __restrict__ eps, int n) {
    int idx = blockIdx.x * 256 + threadIdx.x;
    int v = idx >> 4, j = idx & 15;
    if (v >= n) return;
    float dn = dis[v];
    float z = dn * out[idx] + dn * dn * h2[idx] + b2[j];
    out[idx] = z + eps[idx] * expf(0.5f * z);
}

// ================= fallback (round-7 atomic path) =================
__global__ __launch_bounds__(256) void deg_count_int(const int* __restrict__ dst,
                                                     int* __restrict__ ideg, int e) {
    int i = blockIdx.x * 256 + threadIdx.x;
    if (i < e) atomicAdd(&ideg[dst[i]], 1);
}
__global__ __launch_bounds__(256) void make_dis(const int* __restrict__ ideg,
                                                float* __restrict__ dis, int n) {
    int i = blockIdx.x * 256 + threadIdx.x;
    if (i < n) dis[i] = rsqrtf(1.0f + (float)ideg[i]);
}
__global__ __launch_bounds__(256) void prop(const int* __restrict__ src,
                                            const int* __restrict__ dst,
                                            const unsigned short* __restrict__ hsb,
                                            float* __restrict__ agg, int e) {
    int idx = blockIdx.x * 256 + threadIdx.x;
    int ed = idx >> 4, j = idx & 15;
    if (ed >= e) return;
    int s = src[ed], d = dst[ed];
    atomicAdd(&agg[(size_t)d * HID + j], b2f(hsb[(size_t)s * HID + j]));
}

extern "C" void kernel_launch(void* const* d_in, const int* in_sizes, int n_in,
                              void* d_out, int out_size, void* d_ws, size_t ws_size,
                              hipStream_t stream) {
    const float* x   = (const float*)d_in[0];
    const float* W1  = (const float*)d_in[1];
    const float* b1  = (const float*)d_in[2];
    const float* W2  = (const float*)d_in[3];
    const float* b2  = (const float*)d_in[4];
    const float* eps = (const float*)d_in[5];
    const int*   ei  = (const int*)d_in[6];

    int n = in_sizes[5] / HID;   // 100000
    int e = in_sizes[6] / 2;     // 3200000
    const int* srcs = ei;
    const int* dsts = ei + e;
    float* outf = (float*)d_out;

    int nbkt    = (n + BW - 1) / BW;         // 1563
    int nBlk    = (n + 255) / 256;
    int eBlk    = (e + 255) / 256;
    int mmBlk   = (n + 63) / 64;
    int featBlk = (n * 16 + 255) / 256;
    int chBlk   = (e + CH - 1) / CH;         // 196

    // bucket-path ws: [pk 4e][gcount][goff][gcursor][dis 4n][h1 64n][agg1 64n][hsb 32n][Wt 16K]
    size_t needBucket = (size_t)e * 4 + 3 * (size_t)(MAXB + 2) * 4
                      + (size_t)n * 4 + (size_t)n * 64 * 2 + (size_t)n * 32 + 16384;
    bool bucketPath = (nbkt <= MAXB) && ((size_t)n < (1u << 26)) && (ws_size >= needBucket);

    if (bucketPath) {
        unsigned*       pk      = (unsigned*)d_ws;
        int*            gcount  = (int*)(pk + e);
        int*            goff    = gcount + (MAXB + 2);
        int*            gcursor = goff + (MAXB + 2);
        float*          dis     = (float*)(gcursor + (MAXB + 2));
        float*          h1      = dis + n;
        float*          agg1    = h1 + (size_t)n * HID;
        unsigned short* hsb     = (unsigned short*)(agg1 + (size_t)n * HID);
        unsigned short* Wt      = hsb + (size_t)n * HID;

        hipMemsetAsync(gcount, 0, (size_t)(MAXB + 2) * 4, stream);
        khist<<<chBlk, 1024, 0, stream>>>(dsts, gcount, e, nbkt);
        kscan<<<1, 1024, 0, stream>>>(gcount, goff, gcursor, nbkt);
        kscatter<<<chBlk, 1024, 0, stream>>>(srcs, dsts, gcursor, pk, e, nbkt);
        kdeg<<<nbkt, 256, 0, stream>>>(pk, goff, dis, n);

        prep_wt<<<32, 256, 0, stream>>>(W1, Wt);
        mm1_mfma<<<mmBlk, 256, 0, stream>>>(x, Wt, dis, h1, hsb, n);

        kagg<<<nbkt, 256, 0, stream>>>(pk, goff, hsb, agg1, n);
        mid<<<featBlk, 256, 0, stream>>>(agg1, h1, hsb, dis, b1, W2, n);
        kagg<<<nbkt, 256, 0, stream>>>(pk, goff, hsb, outf, n);
        finalk<<<featBlk, 256, 0, stream>>>(outf, h1, dis, b2, eps, n);
    } else {
        // round-7 path
        int*            ideg = (int*)d_ws;
        float*          dis  = (float*)(ideg + n);
        float*          h1   = dis + n;
        float*          agg1 = h1 + (size_t)n * HID;
        unsigned short* hsb  = (unsigned short*)(agg1 + (size_t)n * HID);
        unsigned short* Wt   = hsb + (size_t)n * HID;

        size_t featBytes = (size_t)n * HID * sizeof(float);
        hipMemsetAsync(ideg, 0, (size_t)n * sizeof(int), stream);
        hipMemsetAsync(agg1, 0, featBytes, stream);
        hipMemsetAsync(outf, 0, featBytes, stream);

        int propBlk = (e * 16 + 255) / 256;
        prep_wt<<<32, 256, 0, stream>>>(W1, Wt);
        deg_count_int<<<eBlk, 256, 0, stream>>>(dsts, ideg, e);
        make_dis<<<nBlk, 256, 0, stream>>>(ideg, dis, n);
        mm1_mfma<<<mmBlk, 256, 0, stream>>>(x, Wt, dis, h1, hsb, n);
        prop<<<propBlk, 256, 0, stream>>>(srcs, dsts, hsb, agg1, e);
        mid<<<featBlk, 256, 0, stream>>>(agg1, h1, hsb, dis, b1, W2, n);
        prop<<<propBlk, 256, 0, stream>>>(srcs, dsts, hsb, outf, e);
        finalk<<<featBlk, 256, 0, stream>>>(outf, h1, dis, b2, eps, n);
    }
}